// Round 5
// baseline (75.947 us; speedup 1.0000x reference)
//
#include <hip/hip_runtime.h>
#include <hip/hip_cooperative_groups.h>
#include <math.h>

namespace cg = cooperative_groups;

// Problem constants (from reference): B=16, D=128, T=512.
#define B_DIM 16
#define D_DIM 128
#define T_DIM 512
#define NT4   128     // float4 per T-row
#define PAD   132     // s_w row pad in floats; %4==0 keeps b128 16B-aligned

// ---------------------------------------------------------------------------
// Cooperative single kernel, 256 blocks x 512 threads (1 block/CU).
//
// Stage 1: 4096 global row-sums (B x 256: Q rows 0..127 | K rows 128..255).
//   Block bid produces rows [bid*16, bid*16+16): 32 lanes/row, 4 float4/lane,
//   fully coalesced; 5-level shfl_xor reduce; result -> ws vec[4096].
//   => queries and keys each read EXACTLY ONCE from HBM.
// grid.sync()
// Stage 2: block = (b = bid&15, c = bid>>4). Load s_vec[256] (this batch's
//   qsums/ksums).
// Stage 3: softmax of all 128 rows: logit = para0/(T*sqrt(T)) * qs_i*ks_j*p2_ij
//   (irfft(...).mean(-1) keeps only the DC bin / T). |logit| <~ 0.2 so no
//   max-subtraction. Weights -> s_w[i][j] (PAD kills phase-D bank conflicts).
// Stage 4: out[b, :, c*32..c*32+31] = attn x values[:, slice].
//   values read EXACTLY ONCE total across the grid.
// ---------------------------------------------------------------------------
__global__ __launch_bounds__(512) void fused_coop_kernel(
    const float* __restrict__ queries,
    const float* __restrict__ keys,
    const float* __restrict__ values,
    const float* __restrict__ para,
    const float* __restrict__ para2,
    float* __restrict__ vec,        // ws: [B][256]  (qsum 0..127 | ksum 128..255)
    float* __restrict__ out) {

    int bid = blockIdx.x;
    int tid = threadIdx.x;

    __shared__ float s_vec[256];
    __shared__ float s_w[D_DIM][PAD];

    // ---- Stage 1: produce 16 of the 4096 row-sums ----
    {
        int row16 = tid >> 5;      // 0..15
        int sub   = tid & 31;      // 32 lanes per row -> 4 float4 each
        int g  = bid * 16 + row16; // global combined row, 0..4095
        int b  = g >> 8;
        int r  = g & 255;
        const float* src = (r < D_DIM)
            ? queries + ((size_t)b * D_DIM + r) * T_DIM
            : keys + ((size_t)b * D_DIM + (r - D_DIM)) * T_DIM;
        const float4* s4 = reinterpret_cast<const float4*>(src);
        float s = 0.f;
        #pragma unroll
        for (int k = 0; k < 4; ++k) {
            float4 v = s4[sub + 32 * k];
            s += (v.x + v.y) + (v.z + v.w);
        }
        #pragma unroll
        for (int off = 16; off > 0; off >>= 1) s += __shfl_xor(s, off, 64);
        if (sub == 0) vec[g] = s;
    }

    __threadfence();
    cg::this_grid().sync();

    int b = bid & 15;
    int c = bid >> 4;              // t-chunk: 32 floats starting at c*32

    // ---- Stage 2: this batch's sums into LDS ----
    if (tid < 256) s_vec[tid] = vec[b * 256 + tid];
    __syncthreads();

    // ---- Stage 3: softmax for all 128 rows; wave w owns rows w*16..+15 ----
    {
        int wave = tid >> 6;
        int lane = tid & 63;
        float cscale = para[0] / (512.0f * sqrtf(512.0f));
        for (int rr = 0; rr < 16; ++rr) {
            int i = wave * 16 + rr;
            float qc = cscale * s_vec[i];
            float l0 = qc * s_vec[128 + lane] * para2[i * D_DIM + lane];
            float l1 = qc * s_vec[128 + lane + 64] * para2[i * D_DIM + lane + 64];
            float e0 = __expf(l0);
            float e1 = __expf(l1);
            float s = e0 + e1;
            #pragma unroll
            for (int off = 32; off > 0; off >>= 1) s += __shfl_xor(s, off, 64);
            float inv = 1.0f / s;
            s_w[i][lane] = e0 * inv;
            s_w[i][lane + 64] = e1 * inv;
        }
    }
    __syncthreads();

    // ---- Stage 4: out[b, :, c*32..+31] = attn x values[:, slice] ----
    {
        int ig = tid >> 3;         // 0..63 -> rows 2ig, 2ig+1
        int t4 = tid & 7;          // float4 within the 32-float slice
        int i0 = ig * 2;
        const float4* v4 = reinterpret_cast<const float4*>(values);
        size_t vbase = (size_t)b * D_DIM * NT4 + (size_t)c * 8 + t4;
        float4 a0 = make_float4(0.f, 0.f, 0.f, 0.f);
        float4 a1 = make_float4(0.f, 0.f, 0.f, 0.f);
        const float4* w0p = reinterpret_cast<const float4*>(&s_w[i0][0]);
        const float4* w1p = reinterpret_cast<const float4*>(&s_w[i0 + 1][0]);

        #define FMA4(A, W, V) \
            A.x += (W) * (V).x; A.y += (W) * (V).y; A.z += (W) * (V).z; A.w += (W) * (V).w;

        #pragma unroll 4
        for (int j4 = 0; j4 < 32; ++j4) {
            float4 w0 = w0p[j4];
            float4 w1 = w1p[j4];
            float4 v0 = v4[vbase + (size_t)(4 * j4 + 0) * NT4];
            float4 v1 = v4[vbase + (size_t)(4 * j4 + 1) * NT4];
            float4 v2 = v4[vbase + (size_t)(4 * j4 + 2) * NT4];
            float4 v3 = v4[vbase + (size_t)(4 * j4 + 3) * NT4];
            FMA4(a0, w0.x, v0) FMA4(a0, w0.y, v1) FMA4(a0, w0.z, v2) FMA4(a0, w0.w, v3)
            FMA4(a1, w1.x, v0) FMA4(a1, w1.y, v1) FMA4(a1, w1.z, v2) FMA4(a1, w1.w, v3)
        }
        #undef FMA4

        float4* o4 = reinterpret_cast<float4*>(out);
        size_t ob = (size_t)(b * D_DIM + i0) * NT4 + (size_t)c * 8 + t4;
        o4[ob] = a0;
        o4[ob + NT4] = a1;
    }
}

extern "C" void kernel_launch(void* const* d_in, const int* in_sizes, int n_in,
                              void* d_out, int out_size, void* d_ws, size_t ws_size,
                              hipStream_t stream) {
    const float* queries = (const float*)d_in[0];  // [B, D, T]
    const float* keys    = (const float*)d_in[1];  // [B, D, T]
    const float* values  = (const float*)d_in[2];  // [B, D, T]
    // d_in[3] = attn_mask (unused)
    const float* para    = (const float*)d_in[4];  // [25]
    const float* para2   = (const float*)d_in[5];  // [D, D]
    float* out = (float*)d_out;                    // [B, D, T] fp32
    float* vec = (float*)d_ws;                     // 4096 floats of scratch

    void* args[] = {(void*)&queries, (void*)&keys, (void*)&values,
                    (void*)&para, (void*)&para2, (void*)&vec, (void*)&out};
    hipLaunchCooperativeKernel((const void*)fused_coop_kernel,
                               dim3(B_DIM * 16), dim3(512), args, 0, stream);
}

// Round 6
// 14.119 us; speedup vs baseline: 5.3792x; 5.3792x over previous
//
#include <hip/hip_runtime.h>
#include <math.h>

// Problem constants (from reference): B=16, D=128, T=512.
#define B_DIM 16
#define D_DIM 128
#define T_DIM 512
#define NT4   128     // float4 per T-row

// ---------------------------------------------------------------------------
// Single kernel, 256 blocks x 1024 threads (16 waves, 4/SIMD — 2x the MLP of
// the 512-thread variant). Block = (b = bid&15, 8-row i-tile = bid>>4).
// 16 tiles of batch b all on XCD b%8 => keys/values L2-resident after first
// touch.
//
// Phase A: ksum for ALL 128 j (keys[b] read per block; L2-served). 16 waves x
//          8 rows: 4-rows-per-wave quad pattern (16 lanes/row, coalesced),
//          4-level shfl_xor reduce.
// Phase B: qsum of the 8 i-rows (waves 0..7, full-wave reduce).
// Phase C: softmax of the 8 rows (waves 0..7): logit =
//          para0/(T*sqrt(T)) * qsum_i * ksum_j * para2_ij  (irfft().mean()
//          keeps only DC/T). Weights transposed s_w[j][r].
// Phase D: out[i-tile, :] = attn x values[b]: 8 j-groups x 16 j x 128 t4;
//          values read exactly once per block; two-stage LDS combine
//          (groups 4..7 -> slots, pre-add by 0..3, final 4-way sum).
// ---------------------------------------------------------------------------
__global__ __launch_bounds__(1024) void fused_attn_kernel(
    const float* __restrict__ queries,
    const float* __restrict__ keys,
    const float* __restrict__ values,
    const float* __restrict__ para,
    const float* __restrict__ para2,
    float* __restrict__ out) {

    int bid = blockIdx.x;
    int b   = bid & 15;
    int i0  = (bid >> 4) * 8;
    int tid = threadIdx.x;
    int wv  = tid >> 6;
    int ln  = tid & 63;

    __shared__ float s_ksum[D_DIM];
    __shared__ float s_q[8];
    __shared__ float s_w[D_DIM][8];          // transposed: [j][row]
    __shared__ float4 s_part[4][8][NT4];     // 64 KB combine buffer

    // ---- Phase A: ksum, 16 waves x 8 rows ----
    const float4* k4 = reinterpret_cast<const float4*>(keys) + (size_t)b * D_DIM * NT4;
    {
        int rr = ln >> 4;      // row within quad (0..3)
        int cc = ln & 15;      // column chunk (0..15)
        #pragma unroll
        for (int it = 0; it < 2; ++it) {
            int row = it * 64 + wv * 4 + rr;
            const float4* kr = k4 + (size_t)row * NT4;
            float s = 0.f;
            #pragma unroll
            for (int k = 0; k < 8; ++k) {
                float4 v = kr[cc + k * 16];
                s += (v.x + v.y) + (v.z + v.w);
            }
            s += __shfl_xor(s, 1, 64);
            s += __shfl_xor(s, 2, 64);
            s += __shfl_xor(s, 4, 64);
            s += __shfl_xor(s, 8, 64);
            if (cc == 0) s_ksum[row] = s;
        }
    }

    // ---- Phase B: qsum rows i0..i0+7 (waves 0..7) ----
    if (wv < 8) {
        const float4* qr = reinterpret_cast<const float4*>(queries)
                           + (size_t)(b * D_DIM + i0 + wv) * NT4;
        float4 a = qr[ln];
        float4 d = qr[ln + 64];
        float s = (a.x + a.y) + (a.z + a.w) + (d.x + d.y) + (d.z + d.w);
        #pragma unroll
        for (int off = 32; off > 0; off >>= 1) s += __shfl_xor(s, off, 64);
        if (ln == 0) s_q[wv] = s;
    }
    __syncthreads();

    // ---- Phase C: softmax of row i0+wv (waves 0..7) ----
    if (wv < 8) {
        float qc = s_q[wv] * (para[0] / (512.0f * sqrtf(512.0f)));
        const float* p2 = para2 + (size_t)(i0 + wv) * D_DIM;
        float l0 = qc * s_ksum[ln] * p2[ln];
        float l1 = qc * s_ksum[ln + 64] * p2[ln + 64];
        float m = fmaxf(l0, l1);
        #pragma unroll
        for (int off = 32; off > 0; off >>= 1) m = fmaxf(m, __shfl_xor(m, off, 64));
        float e0 = __expf(l0 - m);
        float e1 = __expf(l1 - m);
        float s = e0 + e1;
        #pragma unroll
        for (int off = 32; off > 0; off >>= 1) s += __shfl_xor(s, off, 64);
        float inv = 1.0f / s;
        s_w[ln][wv] = e0 * inv;
        s_w[ln + 64][wv] = e1 * inv;
    }
    __syncthreads();

    // ---- Phase D: 8 groups x 16 j x 128 t4 ----
    int g  = tid >> 7;        // j-group 0..7 (each wave lies in one group)
    int t4 = tid & 127;       // float4 column
    const float4* v4 = reinterpret_cast<const float4*>(values) + (size_t)b * D_DIM * NT4;
    float4 acc[8];
    #pragma unroll
    for (int r = 0; r < 8; ++r) acc[r] = make_float4(0.f, 0.f, 0.f, 0.f);

    #define FMA4(A, W) \
        A.x += (W) * v.x; A.y += (W) * v.y; A.z += (W) * v.z; A.w += (W) * v.w;

    int jbeg = g * 16;
    #pragma unroll 4
    for (int j = jbeg; j < jbeg + 16; ++j) {
        float4 v = v4[(size_t)j * NT4 + t4];
        const float4* wp = reinterpret_cast<const float4*>(&s_w[j][0]);  // wave-uniform
        float4 w0 = wp[0];
        float4 w1 = wp[1];
        FMA4(acc[0], w0.x) FMA4(acc[1], w0.y) FMA4(acc[2], w0.z) FMA4(acc[3], w0.w)
        FMA4(acc[4], w1.x) FMA4(acc[5], w1.y) FMA4(acc[6], w1.z) FMA4(acc[7], w1.w)
    }
    #undef FMA4

    // two-stage combine: 8 -> 4 -> 1
    if (g >= 4) {
        #pragma unroll
        for (int r = 0; r < 8; ++r) s_part[g - 4][r][t4] = acc[r];
    }
    __syncthreads();
    if (g < 4) {
        #pragma unroll
        for (int r = 0; r < 8; ++r) {
            float4 p = s_part[g][r][t4];
            acc[r].x += p.x; acc[r].y += p.y; acc[r].z += p.z; acc[r].w += p.w;
            s_part[g][r][t4] = acc[r];
        }
    }
    __syncthreads();
    {
        int r  = tid >> 7;    // 0..7
        int tt = tid & 127;
        float4 p0 = s_part[0][r][tt];
        float4 p1 = s_part[1][r][tt];
        float4 p2 = s_part[2][r][tt];
        float4 p3 = s_part[3][r][tt];
        float4 sum;
        sum.x = (p0.x + p1.x) + (p2.x + p3.x);
        sum.y = (p0.y + p1.y) + (p2.y + p3.y);
        sum.z = (p0.z + p1.z) + (p2.z + p3.z);
        sum.w = (p0.w + p1.w) + (p2.w + p3.w);
        reinterpret_cast<float4*>(out)[(size_t)(b * D_DIM + i0 + r) * NT4 + tt] = sum;
    }
}

extern "C" void kernel_launch(void* const* d_in, const int* in_sizes, int n_in,
                              void* d_out, int out_size, void* d_ws, size_t ws_size,
                              hipStream_t stream) {
    const float* queries = (const float*)d_in[0];  // [B, D, T]
    const float* keys    = (const float*)d_in[1];  // [B, D, T]
    const float* values  = (const float*)d_in[2];  // [B, D, T]
    // d_in[3] = attn_mask (unused)
    const float* para    = (const float*)d_in[4];  // [25]
    const float* para2   = (const float*)d_in[5];  // [D, D]
    float* out = (float*)d_out;                    // [B, D, T] fp32

    fused_attn_kernel<<<B_DIM * (D_DIM / 8), 1024, 0, stream>>>(
        queries, keys, values, para, para2, out);
}